// Round 5
// baseline (523.953 us; speedup 1.0000x reference)
//
#include <hip/hip_runtime.h>
#include <hip/hip_bf16.h>
#include <hip/hip_cooperative_groups.h>

namespace cg = cooperative_groups;

// ---- MoE top-2 fused FFN, single cooperative kernel -------------------------
constexpr int D_    = 512;
constexpr int H_    = 1024;
constexpr int E_    = 8;
constexpr int NTOK_ = 16384;     // B*T
constexpr int MT_   = 64;        // tokens per FFN tile
constexpr float NEG_ = 0.01f;

typedef short s16x8 __attribute__((ext_vector_type(8)));
typedef float f32x4 __attribute__((ext_vector_type(4)));

#define MFMA16(a,b,c) __builtin_amdgcn_mfma_f32_16x16x32_bf16((a),(b),(c),0,0,0)

__device__ __forceinline__ unsigned short f2bf(float f) {
  unsigned u = __float_as_uint(f);
  u += 0x7FFFu + ((u >> 16) & 1u);       // RNE
  return (unsigned short)(u >> 16);
}
__device__ __forceinline__ float bf2f(unsigned u16) {
  return __uint_as_float(u16 << 16);
}
__device__ __forceinline__ float leaky(float v) {
  return v > 0.f ? v : NEG_ * v;
}

struct Params {
  const float *x, *Wr, *br, *W1, *bias1, *W2, *bias2;
  unsigned short *W1s, *W2s;
  int *cnt; float *psum;
  int *tokE, *tokSlot; float *tokW;
  int *posOfTok, *tokOfPos;
  unsigned short *buf;
  float *out, *loss_out;
};

// LDS union (148608 B):
//   phase 1 router : float xl[64][516] @0 (132096) + float wrl[4096] @132096
//                    (16384) + lcnt/gbase/lp @148480
//   phase 2 convert: float ldsf[64][68] @0 (17408)
//   phase 4 ffn    : u16 xs[64][520] @0 (66560) + u16 hs[64][520] @66560
__global__ __launch_bounds__(512, 2) void fused_kernel(Params P) {
  __shared__ __align__(16) char smem[148608];
  cg::grid_group grid = cg::this_grid();
  const int tid  = threadIdx.x;
  const int w    = tid >> 6;
  const int lane = tid & 63;
  const int blk  = blockIdx.x;

  // ============ phase 1: router — 64 tokens/block, coalesced LDS ============
  {
    float (*xl)[516] = (float (*)[516])smem;
    float* wrl  = (float*)(smem + 132096);
    int*   lcnt = (int*)(smem + 148480);
    int*   gb   = (int*)(smem + 148512);
    float* lp   = (float*)(smem + 148544);
    if (tid < E_) { lcnt[tid] = 0; lp[tid] = 0.f; }
    {  // stage Wr (512x8 fp32 = 16KB), coalesced
      const float4* s4 = (const float4*)P.Wr;
      float4* d4 = (float4*)wrl;
      d4[tid * 2] = s4[tid * 2]; d4[tid * 2 + 1] = s4[tid * 2 + 1];
    }
    const int t0 = blk * 64;
    for (int r2 = 0; r2 < 8; r2++) {  // stage 64 x-rows fp32, coalesced
      int row = w * 8 + r2;
      const float4* src = (const float4*)(P.x + (size_t)(t0 + row) * D_);
      float4 a = src[lane * 2], b = src[lane * 2 + 1];
      *(float4*)&xl[row][lane * 8] = a;
      *(float4*)&xl[row][lane * 8 + 4] = b;
    }
    __syncthreads();
    // lane = (tg, eg): token tg of this wave's 8, expert eg
    const int tg = lane >> 3, eg = lane & 7;
    const int tokl = w * 8 + tg;
    float acc = P.br[eg];
    for (int d = 0; d < D_; d += 4) {
      float4 xv = *(const float4*)&xl[tokl][d];   // broadcast across eg lanes
      acc += xv.x * wrl[d * 8 + eg] + xv.y * wrl[d * 8 + 8 + eg] +
             xv.z * wrl[d * 8 + 16 + eg] + xv.w * wrl[d * 8 + 24 + eg];
    }
    float lg[8];
#pragma unroll
    for (int e = 0; e < 8; e++) lg[e] = __shfl(acc, (lane & 56) | e);
    float mx = lg[0];
#pragma unroll
    for (int e = 1; e < 8; e++) mx = fmaxf(mx, lg[e]);
    float p[8], s = 0.f;
#pragma unroll
    for (int e = 0; e < 8; e++) { p[e] = expf(lg[e] - mx); s += p[e]; }
    float inv = 1.f / s;
#pragma unroll
    for (int e = 0; e < 8; e++) p[e] *= inv;
    // top-2, strict > keeps lower index on ties (jax.lax.top_k)
    float m1 = -1.f, m2 = -1.f; int i1 = 0, i2 = 0;
#pragma unroll
    for (int e = 0; e < 8; e++) {
      float pe = p[e];
      if (pe > m1)      { m2 = m1; i2 = i1; m1 = pe; i1 = e; }
      else if (pe > m2) { m2 = pe; i2 = e; }
    }
    int s1 = 0, s2 = 0;
    if (eg == 0) { s1 = atomicAdd(&lcnt[i1], 1); s2 = atomicAdd(&lcnt[i2], 1); }
    float pe = p[eg];
#pragma unroll
    for (int o = 8; o < 64; o <<= 1) pe += __shfl_xor(pe, o);  // sum over tg
    if (tg == 0) atomicAdd(&lp[eg], pe);
    __syncthreads();
    if (tid < E_) {
      gb[tid] = atomicAdd(&P.cnt[tid * 16], lcnt[tid]);  // stride-16: own line
      atomicAdd(&P.psum[tid * 16], lp[tid]);
    }
    __syncthreads();
    if (eg == 0) {
      int t = t0 + tokl;
      P.tokE[2 * t]     = i1; P.tokSlot[2 * t]     = gb[i1] + s1; P.tokW[2 * t]     = m1;
      P.tokE[2 * t + 1] = i2; P.tokSlot[2 * t + 1] = gb[i2] + s2; P.tokW[2 * t + 1] = m2;
    }
    __syncthreads();  // LDS reused next phase
  }

  // ============ phase 2: weight convert (8 64x64 tiles per block) ============
  {
    float (*ldsf)[68] = (float (*)[68])smem;
    for (int ti = 0; ti < 8; ti++) {
      int bid = blk * 8 + ti;        // 0..2047; <1024 -> W1
      bool isW1 = bid < 1024;
      const float* src; int srcStride, e, kt, tc;
      if (isW1) {
        e = bid >> 7; kt = (bid >> 4) & 7; tc = bid & 15; srcStride = 1024;
        src = P.W1 + ((size_t)(e * 512 + kt * 64)) * 1024 + tc * 64;
      } else {
        int b2i = bid - 1024;
        e = b2i >> 7; kt = (b2i >> 3) & 15; tc = b2i & 7; srcStride = 512;
        src = P.W2 + ((size_t)(e * 1024 + kt * 64)) * 512 + tc * 64;
      }
#pragma unroll
      for (int rep = 0; rep < 2; rep++) {
        int row = rep * 32 + (tid >> 4);
        int c4  = (tid & 15) * 4;
        float4 v = *(const float4*)(src + (size_t)row * srcStride + c4);
        ldsf[row][c4] = v.x; ldsf[row][c4 + 1] = v.y;
        ldsf[row][c4 + 2] = v.z; ldsf[row][c4 + 3] = v.w;
      }
      __syncthreads();
      {  // 8 waves x 1 fragment chunk: lane holds B[k0+j][n]
        int ks = w >> 2, nt = w & 3;
        int k0 = ks * 32 + (lane >> 4) * 8;
        int n  = nt * 16 + (lane & 15);
        s16x8 v;
#pragma unroll
        for (int j = 0; j < 8; j++) v[j] = (short)f2bf(ldsf[k0 + j][n]);
        int ntg = tc * 4 + nt, kkg = kt * 2 + ks;
        if (isW1)
          *(s16x8*)(P.W1s + (((size_t)e << 16) + (ntg << 10) + (kkg << 6) + lane) * 8) = v;
        else
          *(s16x8*)(P.W2s + (((size_t)e << 16) + (ntg << 11) + (kkg << 6) + lane) * 8) = v;
      }
      __syncthreads();
    }
  }
  grid.sync();

  // ============ phase 3: assign (pair -> compact position) + loss ============
  {
    if (tid < 128) {
      int p = blk * 128 + tid;
      int te = P.tokE[p], soff = 0;
#pragma unroll
      for (int e2 = 0; e2 < E_; e2++) soff += (e2 < te) ? P.cnt[e2 * 16] : 0;
      int pos = soff + P.tokSlot[p];
      P.posOfTok[p] = pos;
      P.tokOfPos[pos] = p >> 1;
    }
    if (blk == 0 && tid == 0) {
      float l = 0.f;
#pragma unroll
      for (int e = 0; e < E_; e++) {
        float d = 0.125f - P.psum[e * 16] / (float)NTOK_;
        l += d * d;
      }
      *P.loss_out = (l / 8.f) * 1e-4f;
    }
  }
  grid.sync();

  // ============ phase 4: fused two-layer FFN (r4 + per-wave kk rotation) =====
  {
    unsigned short (*xs)[520] = (unsigned short (*)[520])smem;
    unsigned short (*hs)[520] = (unsigned short (*)[520])(smem + 66560);
    const int qm = lane & 15;
    const int qk = (lane >> 4) * 8;
    const int qr = (lane >> 4) * 4;
    const int rot = w * 2;   // stagger waves' kk order: breaks phase-aligned bursts

    for (int vt = blk; vt < 2048; vt += 256) {   // vt&7 == blk&7: XCD pinning kept
      const int e = vt & 7;
      const int tile = vt >> 3;
      int nTok = 0, base0 = 0;
#pragma unroll
      for (int i = 0; i < E_; i++) {
        int ci = P.cnt[i * 16];
        if (i < e) base0 += ci;
        if (i == e) nTok = ci;
      }
      const int start = tile * MT_;
      if (start >= nTok) continue;               // block-uniform
      const int valid = min(MT_, nTok - start);
      const int base = base0 + start;

      for (int r = w; r < MT_; r += 8) {         // stage x tile fp32->bf16
        int tok = P.tokOfPos[base + min(r, valid - 1)];
        const float4* src = (const float4*)(P.x + (size_t)tok * D_);
        float4 a = src[lane * 2], b = src[lane * 2 + 1];
        s16x8 v;
        v[0] = (short)f2bf(a.x); v[1] = (short)f2bf(a.y);
        v[2] = (short)f2bf(a.z); v[3] = (short)f2bf(a.w);
        v[4] = (short)f2bf(b.x); v[5] = (short)f2bf(b.y);
        v[6] = (short)f2bf(b.z); v[7] = (short)f2bf(b.w);
        *(s16x8*)&xs[r][lane * 8] = v;
      }
      __syncthreads();

      f32x4 acc2[4][4];
#pragma unroll
      for (int mi = 0; mi < 4; mi++)
#pragma unroll
        for (int ni = 0; ni < 4; ni++) acc2[mi][ni] = {0.f, 0.f, 0.f, 0.f};

      const unsigned short* B1w = P.W1s + ((size_t)(e * 64 + w * 4) * 16) * 512 + lane * 8;
      const unsigned short* B2w = P.W2s + ((size_t)(e * 32 + w * 4) * 32) * 512 + lane * 8;

      for (int c = 0; c < 2; c++) {
        f32x4 acc1[4][4];
#pragma unroll
        for (int mi = 0; mi < 4; mi++)
#pragma unroll
          for (int ni = 0; ni < 4; ni++) acc1[mi][ni] = {0.f, 0.f, 0.f, 0.f};

        const unsigned short* B1c = B1w + (size_t)(c * 512) * 512;
        float bb[4];
#pragma unroll
        for (int ni = 0; ni < 4; ni++)
          bb[ni] = P.bias1[e * H_ + c * 512 + w * 64 + ni * 16 + qm];

        s16x8 bfp[2][4], afp[2][4];
#pragma unroll
        for (int s = 0; s < 2; s++) {
          int kr = (s + rot) & 15;
#pragma unroll
          for (int ni = 0; ni < 4; ni++)
            bfp[s][ni] = *(const s16x8*)(B1c + (size_t)(ni * 16 + kr) * 512);
#pragma unroll
          for (int mi = 0; mi < 4; mi++)
            afp[s][mi] = *(const s16x8*)&xs[mi * 16 + qm][kr * 32 + qk];
        }
#pragma unroll
        for (int kk = 0; kk < 16; kk++) {
          s16x8 bcur[4], acur[4];
#pragma unroll
          for (int ni = 0; ni < 4; ni++) bcur[ni] = bfp[kk & 1][ni];
#pragma unroll
          for (int mi = 0; mi < 4; mi++) acur[mi] = afp[kk & 1][mi];
          if (kk + 2 < 16) {
            int kr2 = (kk + 2 + rot) & 15;
#pragma unroll
            for (int ni = 0; ni < 4; ni++)
              bfp[kk & 1][ni] = *(const s16x8*)(B1c + (size_t)(ni * 16 + kr2) * 512);
#pragma unroll
            for (int mi = 0; mi < 4; mi++)
              afp[kk & 1][mi] = *(const s16x8*)&xs[mi * 16 + qm][kr2 * 32 + qk];
          }
#pragma unroll
          for (int ni = 0; ni < 4; ni++)
#pragma unroll
            for (int mi = 0; mi < 4; mi++)
              acc1[mi][ni] = MFMA16(acur[mi], bcur[ni], acc1[mi][ni]);
        }
        __syncthreads();   // all waves done reading prior hs

        const unsigned short* B2c = B2w + (size_t)(c * 16) * 512;
        s16x8 b2p[2][4];   // prefetch under hs-write + barrier latency
#pragma unroll
        for (int s = 0; s < 2; s++) {
          int kr = (s + rot) & 15;
#pragma unroll
          for (int ni = 0; ni < 4; ni++)
            b2p[s][ni] = *(const s16x8*)(B2c + (size_t)(ni * 32 + kr) * 512);
        }
#pragma unroll
        for (int ni = 0; ni < 4; ni++) {   // C-layout -> row-major hs
          int hcol = w * 64 + ni * 16 + qm;
#pragma unroll
          for (int mi = 0; mi < 4; mi++)
#pragma unroll
            for (int r4 = 0; r4 < 4; r4++)
              hs[mi * 16 + qr + r4][hcol] = f2bf(leaky(acc1[mi][ni][r4] + bb[ni]));
        }
        __syncthreads();   // hs ready

        s16x8 a2p[2][4];
#pragma unroll
        for (int s = 0; s < 2; s++) {
          int kr = (s + rot) & 15;
#pragma unroll
          for (int mi = 0; mi < 4; mi++)
            a2p[s][mi] = *(const s16x8*)&hs[mi * 16 + qm][kr * 32 + qk];
        }
#pragma unroll
        for (int kk = 0; kk < 16; kk++) {
          s16x8 bcur[4], acur[4];
#pragma unroll
          for (int ni = 0; ni < 4; ni++) bcur[ni] = b2p[kk & 1][ni];
#pragma unroll
          for (int mi = 0; mi < 4; mi++) acur[mi] = a2p[kk & 1][mi];
          if (kk + 2 < 16) {
            int kr2 = (kk + 2 + rot) & 15;
#pragma unroll
            for (int ni = 0; ni < 4; ni++)
              b2p[kk & 1][ni] = *(const s16x8*)(B2c + (size_t)(ni * 32 + kr2) * 512);
#pragma unroll
            for (int mi = 0; mi < 4; mi++)
              a2p[kk & 1][mi] = *(const s16x8*)&hs[mi * 16 + qm][kr2 * 32 + qk];
          }
#pragma unroll
          for (int ni = 0; ni < 4; ni++)
#pragma unroll
            for (int mi = 0; mi < 4; mi++)
              acc2[mi][ni] = MFMA16(acur[mi], bcur[ni], acc2[mi][ni]);
        }
      }

      // epilogue: bias + leaky -> compact bf16 buffer
#pragma unroll
      for (int mi = 0; mi < 4; mi++) {
#pragma unroll
        for (int r4 = 0; r4 < 4; r4++) {
          int row = mi * 16 + qr + r4;
          if (row < valid) {
            size_t rowbase = (size_t)(base + row) * D_;
#pragma unroll
            for (int ni = 0; ni < 4; ni++) {
              int col = w * 64 + ni * 16 + qm;
              float v = leaky(acc2[mi][ni][r4] + P.bias2[e * D_ + col]);
              P.buf[rowbase + col] = f2bf(v);
            }
          }
        }
      }
      __syncthreads();   // xs/hs reuse next vt
    }
  }
  grid.sync();

  // ============ phase 5: combine — out[t] = w0*buf[p0] + w1*buf[p1] ==========
  {
    for (int i = 0; i < 8; i++) {
      int t = blk * 64 + w * 8 + i;
      int p0 = P.posOfTok[2 * t], p1 = P.posOfTok[2 * t + 1];  // wave-uniform
      float w0 = P.tokW[2 * t], w1 = P.tokW[2 * t + 1];
      uint4 u0 = ((const uint4*)(P.buf + (size_t)p0 * D_))[lane];
      uint4 u1 = ((const uint4*)(P.buf + (size_t)p1 * D_))[lane];
      float4 oA, oB;
      oA.x = w0 * bf2f(u0.x & 0xFFFFu) + w1 * bf2f(u1.x & 0xFFFFu);
      oA.y = w0 * bf2f(u0.x >> 16)     + w1 * bf2f(u1.x >> 16);
      oA.z = w0 * bf2f(u0.y & 0xFFFFu) + w1 * bf2f(u1.y & 0xFFFFu);
      oA.w = w0 * bf2f(u0.y >> 16)     + w1 * bf2f(u1.y >> 16);
      oB.x = w0 * bf2f(u0.z & 0xFFFFu) + w1 * bf2f(u1.z & 0xFFFFu);
      oB.y = w0 * bf2f(u0.z >> 16)     + w1 * bf2f(u1.z >> 16);
      oB.z = w0 * bf2f(u0.w & 0xFFFFu) + w1 * bf2f(u1.w & 0xFFFFu);
      oB.w = w0 * bf2f(u0.w >> 16)     + w1 * bf2f(u1.w >> 16);
      float4* dst = (float4*)(P.out + (size_t)t * D_);
      dst[lane * 2]     = oA;
      dst[lane * 2 + 1] = oB;
    }
  }
}

// ---------------------------------------------------------------------------
extern "C" void kernel_launch(void* const* d_in, const int* in_sizes, int n_in,
                              void* d_out, int out_size, void* d_ws, size_t ws_size,
                              hipStream_t stream) {
  char* ws = (char*)d_ws;
  Params P;
  P.x  = (const float*)d_in[0];
  P.Wr = (const float*)d_in[1];
  P.br = (const float*)d_in[2];
  P.W1 = (const float*)d_in[3];
  P.bias1 = (const float*)d_in[4];
  P.W2 = (const float*)d_in[5];
  P.bias2 = (const float*)d_in[6];
  P.out = (float*)d_out;
  P.loss_out = (float*)d_out + (size_t)NTOK_ * D_;

  P.cnt      = (int*)(ws + 0);        // 8 counters, stride-16 ints [zeroed]
  P.psum     = (float*)(ws + 512);    // 8 sums, stride-16 floats  [zeroed]
  P.tokE     = (int*)(ws + 4096);
  P.tokSlot  = (int*)(ws + 4096 + 1 * 131072);
  P.tokW     = (float*)(ws + 4096 + 2 * 131072);
  P.posOfTok = (int*)(ws + 4096 + 3 * 131072);
  P.tokOfPos = (int*)(ws + 4096 + 4 * 131072);
  P.W1s = (unsigned short*)(ws + (1u << 20));              // 8 MB
  P.W2s = (unsigned short*)(ws + (1u << 20) + 16777216u);  // 8 MB
  P.buf = (unsigned short*)(ws + (1u << 20) + 33554432u);  // 32 MB

  hipMemsetAsync(d_ws, 0, 2048, stream);
  void* args[] = { &P };
  hipLaunchCooperativeKernel((void*)fused_kernel, dim3(256), dim3(512),
                             args, 0, stream);
}